// Round 2
// baseline (2478.533 us; speedup 1.0000x reference)
//
#include <hip/hip_runtime.h>
#include <hip/hip_bf16.h>
#include <math.h>

#define B_    2
#define L_    2048
#define E_    1024
#define H_    16
#define DH_   64
#define HID_  4096
#define NROW_ (B_*L_)   // 4096
#define BH_   (B_*H_)   // 32

// ---------------------------------------------------------------------------
// Kernel 1: QKV projection. C = z @ W + b, scattered to (B,H,L,DH) layout.
// 64x64 output tile per block, 256 threads, 4x4 micro-tile per thread.
// ---------------------------------------------------------------------------
__global__ __launch_bounds__(256) void qkv_gemm(
    const float* __restrict__ z,
    const float* __restrict__ Wq, const float* __restrict__ bq,
    const float* __restrict__ Wk, const float* __restrict__ bk,
    const float* __restrict__ Wv, const float* __restrict__ bv,
    float* __restrict__ Qo, float* __restrict__ Ko, float* __restrict__ Vo)
{
    const int which = blockIdx.z;
    const float* W    = (which == 0) ? Wq : (which == 1) ? Wk : Wv;
    const float* bias = (which == 0) ? bq : (which == 1) ? bk : bv;
    float*       out  = (which == 0) ? Qo : (which == 1) ? Ko : Vo;

    __shared__ float As[64][68];
    __shared__ float Bs[64][68];

    const int t  = threadIdx.x;
    const int tx = t & 15, ty = t >> 4;
    const int m0 = blockIdx.x * 64;
    const int n0 = blockIdx.y * 64;     // n0 = h*64  (DH_==64)
    const int h  = blockIdx.y;

    float acc[4][4] = {};

    for (int k0 = 0; k0 < E_; k0 += 64) {
        __syncthreads();
        #pragma unroll
        for (int u = 0; u < 4; ++u) {
            int f   = t + 256 * u;          // float4 id 0..1023
            int row = f >> 4;
            int c4  = (f & 15) << 2;
            *(float4*)&As[row][c4] = *(const float4*)&z[(size_t)(m0 + row) * E_ + k0 + c4];
            *(float4*)&Bs[row][c4] = *(const float4*)&W[(size_t)(k0 + row) * E_ + n0 + c4];
        }
        __syncthreads();

        #pragma unroll
        for (int kc = 0; kc < 16; ++kc) {
            float4 a4[4], b4[4];
            #pragma unroll
            for (int r = 0; r < 4; ++r) a4[r] = *(const float4*)&As[ty * 4 + r][kc * 4];
            #pragma unroll
            for (int q = 0; q < 4; ++q) b4[q] = *(const float4*)&Bs[kc * 4 + q][tx * 4];
            #pragma unroll
            for (int r = 0; r < 4; ++r) {
                const float* ap = reinterpret_cast<const float*>(&a4[r]);
                #pragma unroll
                for (int q = 0; q < 4; ++q) {
                    const float* bp = reinterpret_cast<const float*>(&b4[q]);
                    float av = ap[q];
                    #pragma unroll
                    for (int c = 0; c < 4; ++c)
                        acc[r][c] = fmaf(av, bp[c], acc[r][c]);
                }
            }
        }
    }

    // epilogue: add bias, scatter to (B,H,L,DH)
    #pragma unroll
    for (int r = 0; r < 4; ++r) {
        int gm = m0 + ty * 4 + r;
        int b  = gm >> 11;          // / L_
        int i  = gm & (L_ - 1);
        float4 v;
        v.x = acc[r][0] + bias[n0 + tx * 4 + 0];
        v.y = acc[r][1] + bias[n0 + tx * 4 + 1];
        v.z = acc[r][2] + bias[n0 + tx * 4 + 2];
        v.w = acc[r][3] + bias[n0 + tx * 4 + 3];
        *(float4*)&out[(((size_t)(b * H_ + h) * L_ + i) * DH_) + tx * 4] = v;
    }
}

// ---------------------------------------------------------------------------
// Kernel 2: per-column stats. For each (b,h,j): m_j = max_i S_ij,
// D_j = sum_i x_i*exp(S_ij - m_j), with S = Q.K^T / 8.
// Block: 64 j's for one (b,h); loops over all i-tiles; online updates.
// ---------------------------------------------------------------------------
__global__ __launch_bounds__(256) void col_stats(
    const float* __restrict__ Q, const float* __restrict__ K,
    const float* __restrict__ x,
    float* __restrict__ Mo, float* __restrict__ Do)
{
    __shared__ float Ks[64][68];
    __shared__ float Qs[64][68];
    __shared__ float xs[64];
    __shared__ float redm[16][64];
    __shared__ float redd[16][64];

    const int t  = threadIdx.x;
    const int tx = t & 15, ty = t >> 4;
    const int bh = blockIdx.y;
    const int b  = bh >> 4;             // / H_
    const int j0 = blockIdx.x * 64;

    // stage K tile once (rows j0..j0+63)
    #pragma unroll
    for (int u = 0; u < 4; ++u) {
        int f = t + 256 * u;
        int row = f >> 4, c4 = (f & 15) << 2;
        *(float4*)&Ks[row][c4] = *(const float4*)&K[((size_t)bh * L_ + j0 + row) * DH_ + c4];
    }

    float cm[4], cd[4];
    #pragma unroll
    for (int c = 0; c < 4; ++c) { cm[c] = -1e30f; cd[c] = 0.f; }

    for (int it = 0; it < L_ / 64; ++it) {
        __syncthreads();
        int i0 = it * 64;
        #pragma unroll
        for (int u = 0; u < 4; ++u) {
            int f = t + 256 * u;
            int row = f >> 4, c4 = (f & 15) << 2;
            *(float4*)&Qs[row][c4] = *(const float4*)&Q[((size_t)bh * L_ + i0 + row) * DH_ + c4];
        }
        if (t < 64) xs[t] = x[b * L_ + i0 + t];
        __syncthreads();

        float s[4][4] = {};
        #pragma unroll
        for (int dc = 0; dc < 16; ++dc) {
            float4 a4[4], b4[4];
            #pragma unroll
            for (int r = 0; r < 4; ++r) a4[r] = *(const float4*)&Qs[ty * 4 + r][dc * 4];
            #pragma unroll
            for (int c = 0; c < 4; ++c) b4[c] = *(const float4*)&Ks[tx * 4 + c][dc * 4];
            #pragma unroll
            for (int r = 0; r < 4; ++r)
                #pragma unroll
                for (int c = 0; c < 4; ++c)
                    s[r][c] += a4[r].x * b4[c].x + a4[r].y * b4[c].y +
                               a4[r].z * b4[c].z + a4[r].w * b4[c].w;
        }

        // online (m, d) update per column
        #pragma unroll
        for (int c = 0; c < 4; ++c) {
            #pragma unroll
            for (int r = 0; r < 4; ++r) {
                float sv = s[r][c] * 0.125f;
                float w  = xs[ty * 4 + r];
                if (sv <= cm[c]) {
                    cd[c] += w * __expf(sv - cm[c]);
                } else {
                    cd[c] = cd[c] * __expf(cm[c] - sv) + w;
                    cm[c] = sv;
                }
            }
        }
    }

    __syncthreads();
    #pragma unroll
    for (int c = 0; c < 4; ++c) {
        redm[ty][tx * 4 + c] = cm[c];
        redd[ty][tx * 4 + c] = cd[c];
    }
    __syncthreads();
    if (t < 64) {
        float M = -1e30f;
        #pragma unroll
        for (int u = 0; u < 16; ++u) M = fmaxf(M, redm[u][t]);
        float Dv = 0.f;
        #pragma unroll
        for (int u = 0; u < 16; ++u) Dv += redd[u][t] * __expf(redm[u][t] - M);
        Mo[(size_t)bh * L_ + j0 + t] = M;
        Do[(size_t)bh * L_ + j0 + t] = Dv;
    }
}

// ---------------------------------------------------------------------------
// Kernel 3: O[i,d] = x_i * sum_j exp(S_ij - m_j) * (x_j*V[j,d]/D_j)
// Block: 64 i's for one (b,h); loops over j-tiles; P staged through LDS.
// Writes O in (B*L, E) row-major for the MLP.
// ---------------------------------------------------------------------------
__global__ __launch_bounds__(256) void attn_out(
    const float* __restrict__ Q, const float* __restrict__ K,
    const float* __restrict__ V, const float* __restrict__ x,
    const float* __restrict__ Mo, const float* __restrict__ Do,
    float* __restrict__ O)
{
    __shared__ float Qs[64][68];
    __shared__ float Ks[64][68];
    __shared__ float Vs[64][68];
    __shared__ float Ps[64][68];
    __shared__ float mj[64];

    const int t  = threadIdx.x;
    const int tx = t & 15, ty = t >> 4;
    const int bh = blockIdx.y;
    const int b  = bh >> 4, h = bh & 15;
    const int i0 = blockIdx.x * 64;

    #pragma unroll
    for (int u = 0; u < 4; ++u) {
        int f = t + 256 * u;
        int row = f >> 4, c4 = (f & 15) << 2;
        *(float4*)&Qs[row][c4] = *(const float4*)&Q[((size_t)bh * L_ + i0 + row) * DH_ + c4];
    }

    float acc[4][4] = {};

    for (int jt = 0; jt < L_ / 64; ++jt) {
        int j0 = jt * 64;
        __syncthreads();
        #pragma unroll
        for (int u = 0; u < 4; ++u) {
            int f = t + 256 * u;
            int row = f >> 4, c4 = (f & 15) << 2;
            *(float4*)&Ks[row][c4] = *(const float4*)&K[((size_t)bh * L_ + j0 + row) * DH_ + c4];
            float4 vv = *(const float4*)&V[((size_t)bh * L_ + j0 + row) * DH_ + c4];
            float sc  = x[b * L_ + j0 + row] / Do[(size_t)bh * L_ + j0 + row];
            vv.x *= sc; vv.y *= sc; vv.z *= sc; vv.w *= sc;
            *(float4*)&Vs[row][c4] = vv;
        }
        if (t < 64) mj[t] = Mo[(size_t)bh * L_ + j0 + t];
        __syncthreads();

        // S tile = Q.K^T
        float s[4][4] = {};
        #pragma unroll
        for (int dc = 0; dc < 16; ++dc) {
            float4 a4[4], b4[4];
            #pragma unroll
            for (int r = 0; r < 4; ++r) a4[r] = *(const float4*)&Qs[ty * 4 + r][dc * 4];
            #pragma unroll
            for (int c = 0; c < 4; ++c) b4[c] = *(const float4*)&Ks[tx * 4 + c][dc * 4];
            #pragma unroll
            for (int r = 0; r < 4; ++r)
                #pragma unroll
                for (int c = 0; c < 4; ++c)
                    s[r][c] += a4[r].x * b4[c].x + a4[r].y * b4[c].y +
                               a4[r].z * b4[c].z + a4[r].w * b4[c].w;
        }
        #pragma unroll
        for (int r = 0; r < 4; ++r)
            #pragma unroll
            for (int c = 0; c < 4; ++c)
                Ps[ty * 4 + r][tx * 4 + c] = __expf(s[r][c] * 0.125f - mj[tx * 4 + c]);
        __syncthreads();

        // acc += P(64x64) @ Vs(64x64)
        #pragma unroll
        for (int kc = 0; kc < 16; ++kc) {
            float4 a4[4], b4[4];
            #pragma unroll
            for (int r = 0; r < 4; ++r) a4[r] = *(const float4*)&Ps[ty * 4 + r][kc * 4];
            #pragma unroll
            for (int q = 0; q < 4; ++q) b4[q] = *(const float4*)&Vs[kc * 4 + q][tx * 4];
            #pragma unroll
            for (int r = 0; r < 4; ++r) {
                const float* ap = reinterpret_cast<const float*>(&a4[r]);
                #pragma unroll
                for (int q = 0; q < 4; ++q) {
                    const float* bp = reinterpret_cast<const float*>(&b4[q]);
                    float av = ap[q];
                    #pragma unroll
                    for (int c = 0; c < 4; ++c)
                        acc[r][c] = fmaf(av, bp[c], acc[r][c]);
                }
            }
        }
    }

    // epilogue: scale by x_i, write O row-major (B*L, E)
    #pragma unroll
    for (int r = 0; r < 4; ++r) {
        int gi   = i0 + ty * 4 + r;
        float xi = x[b * L_ + gi];
        float4 v;
        v.x = acc[r][0] * xi;
        v.y = acc[r][1] * xi;
        v.z = acc[r][2] * xi;
        v.w = acc[r][3] * xi;
        *(float4*)&O[((size_t)(b * L_ + gi)) * E_ + h * DH_ + tx * 4] = v;
    }
}

// ---------------------------------------------------------------------------
// Kernel 4: fused MLP. y[n] = sum_hd gelu(O[n,:]·W1[:,hd] + b1[hd]) * W2[hd] + b2
// Block: 16 rows, 512 threads; each thread owns 4 consecutive hidden units
// per pass (2 passes cover HID=4096); W1 reads coalesced & reused x16 rows.
// ---------------------------------------------------------------------------
__global__ __launch_bounds__(512) void mlp_fused(
    const float* __restrict__ O, const float* __restrict__ W1,
    const float* __restrict__ b1, const float* __restrict__ W2,
    const float* __restrict__ b2, float* __restrict__ y)
{
    __shared__ float Os[16][1024];
    __shared__ float red[16][8];

    const int t    = threadIdx.x;
    const int row0 = blockIdx.x * 16;

    // 16 rows x 1024 cols = 4096 float4s; 256 float4s per row.
    #pragma unroll
    for (int u = 0; u < 8; ++u) {
        int f4  = t + 512 * u;          // float4 id 0..4095
        int row = f4 >> 8;              // /256
        int c4  = (f4 & 255) << 2;
        *(float4*)&Os[row][c4] = *(const float4*)&O[(size_t)(row0 + row) * E_ + c4];
    }
    __syncthreads();

    float ypart[16] = {};

    for (int p = 0; p < 2; ++p) {
        const int hd = p * 2048 + t * 4;
        float acc[16][4] = {};
        #pragma unroll 2
        for (int k = 0; k < E_; ++k) {
            float4 w = *(const float4*)&W1[(size_t)k * HID_ + hd];
            #pragma unroll
            for (int r = 0; r < 16; ++r) {
                float o = Os[r][k];
                acc[r][0] = fmaf(o, w.x, acc[r][0]);
                acc[r][1] = fmaf(o, w.y, acc[r][1]);
                acc[r][2] = fmaf(o, w.z, acc[r][2]);
                acc[r][3] = fmaf(o, w.w, acc[r][3]);
            }
        }
        #pragma unroll
        for (int c = 0; c < 4; ++c) {
            float w2 = W2[hd + c];
            float bb = b1[hd + c];
            #pragma unroll
            for (int r = 0; r < 16; ++r) {
                float hv = acc[r][c] + bb;
                float g  = 0.5f * hv * (1.0f + erff(hv * 0.70710678118654752f));
                ypart[r] = fmaf(g, w2, ypart[r]);
            }
        }
    }

    // block reduction: 8 waves of 64
    #pragma unroll
    for (int r = 0; r < 16; ++r) {
        float v = ypart[r];
        #pragma unroll
        for (int off = 32; off > 0; off >>= 1) v += __shfl_down(v, off);
        if ((t & 63) == 0) red[r][t >> 6] = v;
    }
    __syncthreads();
    if (t < 16) {
        float s = 0.f;
        #pragma unroll
        for (int wv = 0; wv < 8; ++wv) s += red[t][wv];
        y[row0 + t] = s + b2[0];
    }
}

// ---------------------------------------------------------------------------
extern "C" void kernel_launch(void* const* d_in, const int* in_sizes, int n_in,
                              void* d_out, int out_size, void* d_ws, size_t ws_size,
                              hipStream_t stream)
{
    const float* x  = (const float*)d_in[0];
    const float* z  = (const float*)d_in[1];
    const float* Wq = (const float*)d_in[2];
    const float* bq = (const float*)d_in[3];
    const float* Wk = (const float*)d_in[4];
    const float* bk = (const float*)d_in[5];
    const float* Wv = (const float*)d_in[6];
    const float* bv = (const float*)d_in[7];
    const float* W1 = (const float*)d_in[8];
    const float* b1 = (const float*)d_in[9];
    const float* W2 = (const float*)d_in[10];
    const float* b2 = (const float*)d_in[11];
    float* y = (float*)d_out;

    float* ws = (float*)d_ws;
    float* Qw = ws;                                   // BH*L*DH = 4194304
    float* Kw = Qw + (size_t)NROW_ * E_;
    float* Vw = Kw + (size_t)NROW_ * E_;
    float* Ow = Vw + (size_t)NROW_ * E_;              // (B*L, E) row-major
    float* Mw = Ow + (size_t)NROW_ * E_;              // BH*L
    float* Dw = Mw + (size_t)BH_ * L_;                // BH*L

    qkv_gemm<<<dim3(NROW_ / 64, E_ / 64, 3), 256, 0, stream>>>(
        z, Wq, bq, Wk, bk, Wv, bv, Qw, Kw, Vw);

    col_stats<<<dim3(L_ / 64, BH_), 256, 0, stream>>>(Qw, Kw, x, Mw, Dw);

    attn_out<<<dim3(L_ / 64, BH_), 256, 0, stream>>>(Qw, Kw, Vw, x, Mw, Dw, Ow);

    mlp_fused<<<dim3(NROW_ / 16), 512, 0, stream>>>(Ow, W1, b1, W2, b2, y);
}

// Round 3
// 936.385 us; speedup vs baseline: 2.6469x; 2.6469x over previous
//
#include <hip/hip_runtime.h>
#include <hip/hip_bf16.h>
#include <math.h>

#define B_    2
#define L_    2048
#define E_    1024
#define H_    16
#define DH_   64
#define HID_  4096
#define NROW_ (B_*L_)   // 4096
#define BH_   (B_*H_)   // 32

typedef __attribute__((ext_vector_type(8)))  short short8v;
typedef __attribute__((ext_vector_type(16))) float f32x16;

#define MFMA32(A, Bv, C) __builtin_amdgcn_mfma_f32_32x32x16_bf16((A), (Bv), (C), 0, 0, 0)

__device__ __forceinline__ unsigned short f2bf(float f) {
    union { float f; unsigned u; } v; v.f = f;
    unsigned r = v.u + 0x7FFF + ((v.u >> 16) & 1);   // RNE
    return (unsigned short)(r >> 16);
}
__device__ __forceinline__ float bf2f(unsigned short u) {
    union { unsigned u; float f; } v; v.u = ((unsigned)u) << 16;
    return v.f;
}

// ---------------------------------------------------------------------------
// Kernel 1: QKV projection (fp32 compute), bf16 output scattered to (BH,L,DH).
// ---------------------------------------------------------------------------
__global__ __launch_bounds__(256) void qkv_gemm(
    const float* __restrict__ z,
    const float* __restrict__ Wq, const float* __restrict__ bq,
    const float* __restrict__ Wk, const float* __restrict__ bk,
    const float* __restrict__ Wv, const float* __restrict__ bv,
    unsigned short* __restrict__ Qo, unsigned short* __restrict__ Ko,
    unsigned short* __restrict__ Vo)
{
    const int which = blockIdx.z;
    const float* W    = (which == 0) ? Wq : (which == 1) ? Wk : Wv;
    const float* bias = (which == 0) ? bq : (which == 1) ? bk : bv;
    unsigned short* out = (which == 0) ? Qo : (which == 1) ? Ko : Vo;

    __shared__ float As[64][68];
    __shared__ float Bs[64][68];

    const int t  = threadIdx.x;
    const int tx = t & 15, ty = t >> 4;
    const int m0 = blockIdx.x * 64;
    const int n0 = blockIdx.y * 64;
    const int h  = blockIdx.y;

    float acc[4][4] = {};

    for (int k0 = 0; k0 < E_; k0 += 64) {
        __syncthreads();
        #pragma unroll
        for (int u = 0; u < 4; ++u) {
            int f   = t + 256 * u;
            int row = f >> 4;
            int c4  = (f & 15) << 2;
            *(float4*)&As[row][c4] = *(const float4*)&z[(size_t)(m0 + row) * E_ + k0 + c4];
            *(float4*)&Bs[row][c4] = *(const float4*)&W[(size_t)(k0 + row) * E_ + n0 + c4];
        }
        __syncthreads();

        #pragma unroll
        for (int kc = 0; kc < 16; ++kc) {
            float4 a4[4], b4[4];
            #pragma unroll
            for (int r = 0; r < 4; ++r) a4[r] = *(const float4*)&As[ty * 4 + r][kc * 4];
            #pragma unroll
            for (int q = 0; q < 4; ++q) b4[q] = *(const float4*)&Bs[kc * 4 + q][tx * 4];
            #pragma unroll
            for (int r = 0; r < 4; ++r) {
                const float* ap = reinterpret_cast<const float*>(&a4[r]);
                #pragma unroll
                for (int q = 0; q < 4; ++q) {
                    const float* bp = reinterpret_cast<const float*>(&b4[q]);
                    float av = ap[q];
                    #pragma unroll
                    for (int c = 0; c < 4; ++c)
                        acc[r][c] = fmaf(av, bp[c], acc[r][c]);
                }
            }
        }
    }

    #pragma unroll
    for (int r = 0; r < 4; ++r) {
        int gm = m0 + ty * 4 + r;
        int b  = gm >> 11;
        int i  = gm & (L_ - 1);
        ushort4 o;
        o.x = f2bf(acc[r][0] + bias[n0 + tx * 4 + 0]);
        o.y = f2bf(acc[r][1] + bias[n0 + tx * 4 + 1]);
        o.z = f2bf(acc[r][2] + bias[n0 + tx * 4 + 2]);
        o.w = f2bf(acc[r][3] + bias[n0 + tx * 4 + 3]);
        *(ushort4*)&out[(((size_t)(b * H_ + h) * L_ + i) * DH_) + tx * 4] = o;
    }
}

// ---------------------------------------------------------------------------
// Kernel 2: column stats via MFMA. S^T = K·Q^T (32x32x16 bf16).
// Block = 4 waves; wave owns 32 j's (K-frags in registers). Loop i in 32-chunks.
// Per-lane online (m,d) over its i-subset, shfl_xor merge at end.
// ---------------------------------------------------------------------------
__global__ __launch_bounds__(256) void col_stats_mfma(
    const unsigned short* __restrict__ Qb, const unsigned short* __restrict__ Kb,
    const float* __restrict__ x,
    float* __restrict__ Mo, float* __restrict__ Do)
{
    __shared__ unsigned short Qlds[32 * 64];
    __shared__ float xlds[L_];

    const int t    = threadIdx.x;
    const int lane = t & 63;
    const int wv   = t >> 6;
    const int l31  = lane & 31;
    const int hq   = lane >> 5;          // 0/1
    const int bh   = blockIdx.y;
    const int b    = bh >> 4;
    const int j0   = blockIdx.x * 128 + wv * 32;

    // stage full x row (8KB)
    #pragma unroll
    for (int u = 0; u < 2; ++u) {
        int f = t + 256 * u;
        *(float4*)&xlds[f * 4] = *(const float4*)&x[(size_t)b * L_ + f * 4];
    }

    // K fragments in registers: row j = j0 + l31, k(dh) = c*16 + hq*8 + 0..7
    short8v kf[4];
    {
        const unsigned short* kp = Kb + ((size_t)bh * L_ + j0 + l31) * DH_ + hq * 8;
        #pragma unroll
        for (int c = 0; c < 4; ++c) kf[c] = *(const short8v*)(kp + c * 16);
    }

    float m[16], d[16];
    #pragma unroll
    for (int r = 0; r < 16; ++r) { m[r] = -1e30f; d[r] = 0.f; }

    for (int ich = 0; ich < L_ / 32; ++ich) {
        // stage Q rows [ich*32 .. +31] (4KB), swizzled
        int row = t >> 3, sl = t & 7;
        short8v qv = *(const short8v*)&Qb[((size_t)bh * L_ + ich * 32 + row) * DH_ + sl * 8];
        __syncthreads();
        *(short8v*)&Qlds[row * 64 + (sl ^ (row & 7)) * 8] = qv;
        __syncthreads();

        f32x16 acc = {};
        #pragma unroll
        for (int c = 0; c < 4; ++c) {
            short8v qf = *(const short8v*)&Qlds[l31 * 64 + (((c * 2 + hq)) ^ (l31 & 7)) * 8];
            acc = MFMA32(kf[c], qf, acc);
        }

        float xi = xlds[ich * 32 + l31];
        #pragma unroll
        for (int r = 0; r < 16; ++r) {
            float s  = acc[r] * 0.125f;
            float mn = fmaxf(m[r], s);
            d[r] = d[r] * __expf(m[r] - mn) + xi * __expf(s - mn);
            m[r] = mn;
        }
    }

    // merge across the 32 lanes sharing the same row set
    #pragma unroll
    for (int r = 0; r < 16; ++r) {
        #pragma unroll
        for (int off = 16; off > 0; off >>= 1) {
            float m2 = __shfl_xor(m[r], off);
            float d2 = __shfl_xor(d[r], off);
            float M  = fmaxf(m[r], m2);
            d[r] = d[r] * __expf(m[r] - M) + d2 * __expf(m2 - M);
            m[r] = M;
        }
    }
    if (l31 == 0) {
        #pragma unroll
        for (int r = 0; r < 16; ++r) {
            int j = j0 + 4 * hq + (r & 3) + 8 * (r >> 2);
            Mo[(size_t)bh * L_ + j] = m[r];
            Do[(size_t)bh * L_ + j] = d[r];
        }
    }
}

// ---------------------------------------------------------------------------
// Kernel 3: Vt[bh][dh][j] = bf16( x_j * V[bh][j][dh] * exp(-M_j) / D_j )
// ---------------------------------------------------------------------------
__global__ __launch_bounds__(256) void vt_prep(
    const unsigned short* __restrict__ Vb, const float* __restrict__ x,
    const float* __restrict__ Mo, const float* __restrict__ Do,
    unsigned short* __restrict__ Vt)
{
    const int bh = blockIdx.y;
    const int b  = bh >> 4;
    const int j  = blockIdx.x * 256 + threadIdx.x;
    const float s = x[(size_t)b * L_ + j] * __expf(-Mo[(size_t)bh * L_ + j]) / Do[(size_t)bh * L_ + j];
    const unsigned short* vp = Vb + ((size_t)bh * L_ + j) * DH_;
    #pragma unroll
    for (int c = 0; c < 16; ++c) {
        ushort4 v = *(const ushort4*)&vp[c * 4];
        Vt[((size_t)bh * DH_ + c * 4 + 0) * L_ + j] = f2bf(bf2f(v.x) * s);
        Vt[((size_t)bh * DH_ + c * 4 + 1) * L_ + j] = f2bf(bf2f(v.y) * s);
        Vt[((size_t)bh * DH_ + c * 4 + 2) * L_ + j] = f2bf(bf2f(v.z) * s);
        Vt[((size_t)bh * DH_ + c * 4 + 3) * L_ + j] = f2bf(bf2f(v.w) * s);
    }
}

// ---------------------------------------------------------------------------
// Kernel 4: attention output via MFMA.
// Block = 4 waves, i-tile 128 (wave: 32 i). Loop j in 64-tiles:
//   S^T = K·Q^T  -> P = exp(S) packed bf16 -> LDS (per-wave) -> O += P·Vt^T.
// Epilogue: O[i][h*64+dh] = x_i * acc (fp32, (B*L,E) row-major).
// ---------------------------------------------------------------------------
__global__ __launch_bounds__(256) void attn_out_mfma(
    const unsigned short* __restrict__ Qb, const unsigned short* __restrict__ Kb,
    const unsigned short* __restrict__ Vt, const float* __restrict__ x,
    float* __restrict__ O)
{
    __shared__ unsigned short Klds[64 * 64];
    __shared__ unsigned short Vlds[64 * 64];
    __shared__ unsigned short Plds[4 * 32 * 64];

    const int t    = threadIdx.x;
    const int lane = t & 63;
    const int wv   = t >> 6;
    const int l31  = lane & 31;
    const int hq   = lane >> 5;
    const int bh   = blockIdx.y;
    const int b    = bh >> 4, hh = bh & 15;
    const int iw   = blockIdx.x * 128 + wv * 32;

    // Q fragments in registers: row i = iw + l31, k(dh) = c*16 + hq*8
    short8v qf[4];
    {
        const unsigned short* qp = Qb + ((size_t)bh * L_ + iw + l31) * DH_ + hq * 8;
        #pragma unroll
        for (int c = 0; c < 4; ++c) qf[c] = *(const short8v*)(qp + c * 16);
    }

    f32x16 accO0 = {}, accO1 = {};
    char* Pw = (char*)(Plds + wv * 2048);

    for (int jt = 0; jt < L_ / 64; ++jt) {
        int j0 = jt * 64;
        // stage K (64x64) and Vt (64x64) bf16, swizzled
        short8v kv[2], vv[2];
        #pragma unroll
        for (int u = 0; u < 2; ++u) {
            int f = t + 256 * u, row = f >> 3, sl = f & 7;
            kv[u] = *(const short8v*)&Kb[((size_t)bh * L_ + j0 + row) * DH_ + sl * 8];
            vv[u] = *(const short8v*)&Vt[((size_t)bh * DH_ + row) * L_ + j0 + sl * 8];
        }
        __syncthreads();
        #pragma unroll
        for (int u = 0; u < 2; ++u) {
            int f = t + 256 * u, row = f >> 3, sl = f & 7;
            *(short8v*)&Klds[row * 64 + (sl ^ (row & 7)) * 8] = kv[u];
            *(short8v*)&Vlds[row * 64 + (sl ^ (row & 7)) * 8] = vv[u];
        }
        __syncthreads();

        // S^T and P (per jsub of 32 j)
        #pragma unroll
        for (int js = 0; js < 2; ++js) {
            f32x16 as = {};
            #pragma unroll
            for (int c = 0; c < 4; ++c) {
                int krow = js * 32 + l31;
                short8v kfr = *(const short8v*)&Klds[krow * 64 + ((c * 2 + hq) ^ (krow & 7)) * 8];
                as = MFMA32(kfr, qf[c], as);
            }
            #pragma unroll
            for (int q = 0; q < 4; ++q) {
                float p0 = __expf(as[4 * q + 0] * 0.125f);
                float p1 = __expf(as[4 * q + 1] * 0.125f);
                float p2 = __expf(as[4 * q + 2] * 0.125f);
                float p3 = __expf(as[4 * q + 3] * 0.125f);
                uint2 pk;
                pk.x = (unsigned)f2bf(p0) | ((unsigned)f2bf(p1) << 16);
                pk.y = (unsigned)f2bf(p2) | ((unsigned)f2bf(p3) << 16);
                int jb   = js * 64 + 8 * hq + 16 * q;             // byte offset of j within row
                *(uint2*)(Pw + l31 * 128 + (jb ^ ((l31 & 7) << 4))) = pk;
            }
        }

        // O += P · Vt^T
        short8v pf[4];
        #pragma unroll
        for (int c = 0; c < 4; ++c)
            pf[c] = *(const short8v*)(Pw + l31 * 128 + (((c * 16 + hq * 8) * 2) ^ ((l31 & 7) << 4)));
        #pragma unroll
        for (int c = 0; c < 4; ++c) {
            int r0 = l31, r1 = 32 + l31;
            short8v vf0 = *(const short8v*)&Vlds[r0 * 64 + ((c * 2 + hq) ^ (r0 & 7)) * 8];
            short8v vf1 = *(const short8v*)&Vlds[r1 * 64 + ((c * 2 + hq) ^ (r1 & 7)) * 8];
            accO0 = MFMA32(pf[c], vf0, accO0);
            accO1 = MFMA32(pf[c], vf1, accO1);
        }
        __syncthreads();
    }

    // epilogue: scale by x_i, write fp32 O (B*L, E)
    #pragma unroll
    for (int q = 0; q < 4; ++q) {
        float4 xq = *(const float4*)&x[(size_t)b * L_ + iw + 4 * hq + 8 * q];
        const float xs[4] = { xq.x, xq.y, xq.z, xq.w };
        #pragma unroll
        for (int k = 0; k < 4; ++k) {
            int r    = q * 4 + k;
            int irow = iw + 4 * hq + 8 * q + k;
            size_t base = ((size_t)b * L_ + irow) * E_ + hh * DH_;
            O[base + l31]      = accO0[r] * xs[k];
            O[base + 32 + l31] = accO1[r] * xs[k];
        }
    }
}

// ---------------------------------------------------------------------------
// Kernel 5: fused MLP (fp32), unchanged.
// ---------------------------------------------------------------------------
__global__ __launch_bounds__(512) void mlp_fused(
    const float* __restrict__ O, const float* __restrict__ W1,
    const float* __restrict__ b1, const float* __restrict__ W2,
    const float* __restrict__ b2, float* __restrict__ y)
{
    __shared__ float Os[16][1024];
    __shared__ float red[16][8];

    const int t    = threadIdx.x;
    const int row0 = blockIdx.x * 16;

    #pragma unroll
    for (int u = 0; u < 8; ++u) {
        int f4  = t + 512 * u;
        int row = f4 >> 8;
        int c4  = (f4 & 255) << 2;
        *(float4*)&Os[row][c4] = *(const float4*)&O[(size_t)(row0 + row) * E_ + c4];
    }
    __syncthreads();

    float ypart[16] = {};

    for (int p = 0; p < 2; ++p) {
        const int hd = p * 2048 + t * 4;
        float acc[16][4] = {};
        #pragma unroll 2
        for (int k = 0; k < E_; ++k) {
            float4 w = *(const float4*)&W1[(size_t)k * HID_ + hd];
            #pragma unroll
            for (int r = 0; r < 16; ++r) {
                float o = Os[r][k];
                acc[r][0] = fmaf(o, w.x, acc[r][0]);
                acc[r][1] = fmaf(o, w.y, acc[r][1]);
                acc[r][2] = fmaf(o, w.z, acc[r][2]);
                acc[r][3] = fmaf(o, w.w, acc[r][3]);
            }
        }
        #pragma unroll
        for (int c = 0; c < 4; ++c) {
            float w2 = W2[hd + c];
            float bb = b1[hd + c];
            #pragma unroll
            for (int r = 0; r < 16; ++r) {
                float hv = acc[r][c] + bb;
                float g  = 0.5f * hv * (1.0f + erff(hv * 0.70710678118654752f));
                ypart[r] = fmaf(g, w2, ypart[r]);
            }
        }
    }

    #pragma unroll
    for (int r = 0; r < 16; ++r) {
        float v = ypart[r];
        #pragma unroll
        for (int off = 32; off > 0; off >>= 1) v += __shfl_down(v, off);
        if ((t & 63) == 0) red[r][t >> 6] = v;
    }
    __syncthreads();
    if (t < 16) {
        float s = 0.f;
        #pragma unroll
        for (int wv = 0; wv < 8; ++wv) s += red[t][wv];
        y[row0 + t] = s + b2[0];
    }
}

// ---------------------------------------------------------------------------
extern "C" void kernel_launch(void* const* d_in, const int* in_sizes, int n_in,
                              void* d_out, int out_size, void* d_ws, size_t ws_size,
                              hipStream_t stream)
{
    const float* x  = (const float*)d_in[0];
    const float* z  = (const float*)d_in[1];
    const float* Wq = (const float*)d_in[2];
    const float* bq = (const float*)d_in[3];
    const float* Wk = (const float*)d_in[4];
    const float* bk = (const float*)d_in[5];
    const float* Wv = (const float*)d_in[6];
    const float* bv = (const float*)d_in[7];
    const float* W1 = (const float*)d_in[8];
    const float* b1 = (const float*)d_in[9];
    const float* W2 = (const float*)d_in[10];
    const float* b2 = (const float*)d_in[11];
    float* y = (float*)d_out;

    const size_t NBH = (size_t)BH_ * L_ * DH_;   // 4.19M elems
    char* ws = (char*)d_ws;
    unsigned short* Qb = (unsigned short*)ws;
    unsigned short* Kb = Qb + NBH;
    unsigned short* Vb = Kb + NBH;
    unsigned short* Vt = Vb + NBH;
    float* Ow = (float*)(Vt + NBH);                       // (B*L, E) fp32
    float* Mw = Ow + (size_t)NROW_ * E_;
    float* Dw = Mw + (size_t)BH_ * L_;

    qkv_gemm<<<dim3(NROW_ / 64, E_ / 64, 3), 256, 0, stream>>>(
        z, Wq, bq, Wk, bk, Wv, bv, Qb, Kb, Vb);

    col_stats_mfma<<<dim3(L_ / 128, BH_), 256, 0, stream>>>(Qb, Kb, x, Mw, Dw);

    vt_prep<<<dim3(L_ / 256, BH_), 256, 0, stream>>>(Vb, x, Mw, Dw, Vt);

    attn_out_mfma<<<dim3(L_ / 128, BH_), 256, 0, stream>>>(Qb, Kb, Vt, x, Ow);

    mlp_fused<<<dim3(NROW_ / 16), 512, 0, stream>>>(Ow, W1, b1, W2, b2, y);
}

// Round 4
// 347.750 us; speedup vs baseline: 7.1273x; 2.6927x over previous
//
#include <hip/hip_runtime.h>
#include <hip/hip_bf16.h>
#include <math.h>

#define B_    2
#define L_    2048
#define E_    1024
#define H_    16
#define DH_   64
#define HID_  4096
#define NROW_ (B_*L_)   // 4096
#define BH_   (B_*H_)   // 32

typedef __attribute__((ext_vector_type(8)))  short short8v;
typedef __attribute__((ext_vector_type(16))) float f32x16;

#define MFMA32(A, Bv, C) __builtin_amdgcn_mfma_f32_32x32x16_bf16((A), (Bv), (C), 0, 0, 0)

__device__ __forceinline__ unsigned short f2bf(float f) {
    union { float f; unsigned u; } v; v.f = f;
    unsigned r = v.u + 0x7FFF + ((v.u >> 16) & 1);   // RNE
    return (unsigned short)(r >> 16);
}
__device__ __forceinline__ float bf2f(unsigned short u) {
    union { unsigned u; float f; } v; v.u = ((unsigned)u) << 16;
    return v.f;
}

// ---------------------------------------------------------------------------
// Prep A: split z (fp32, NROW x E) into hi/lo bf16 planes (same layout).
// ---------------------------------------------------------------------------
__global__ __launch_bounds__(256) void split_z(
    const float* __restrict__ z,
    unsigned short* __restrict__ zhi, unsigned short* __restrict__ zlo)
{
    const size_t i = ((size_t)blockIdx.x * 256 + threadIdx.x) * 8;
    float v[8];
    *(float4*)&v[0] = *(const float4*)&z[i];
    *(float4*)&v[4] = *(const float4*)&z[i + 4];
    unsigned short h[8], l[8];
    #pragma unroll
    for (int j = 0; j < 8; ++j) {
        h[j] = f2bf(v[j]);
        l[j] = f2bf(v[j] - bf2f(h[j]));
    }
    *(short8v*)&zhi[i] = *(short8v*)h;
    *(short8v*)&zlo[i] = *(short8v*)l;
}

// ---------------------------------------------------------------------------
// Prep B: transpose+cast Wq/Wk/Wv (ExE fp32) -> Wt (n-major, bf16).
// ---------------------------------------------------------------------------
__global__ __launch_bounds__(256) void wprep3(
    const float* __restrict__ Wq, const float* __restrict__ Wk,
    const float* __restrict__ Wv,
    unsigned short* __restrict__ Tq, unsigned short* __restrict__ Tk,
    unsigned short* __restrict__ Tv)
{
    const float* src = (blockIdx.z == 0) ? Wq : (blockIdx.z == 1) ? Wk : Wv;
    unsigned short* dst = (blockIdx.z == 0) ? Tq : (blockIdx.z == 1) ? Tk : Tv;

    __shared__ float tile[64][65];
    const int t  = threadIdx.x;
    const int r0 = blockIdx.y * 64, c0 = blockIdx.x * 64;

    #pragma unroll
    for (int u = 0; u < 4; ++u) {
        int f = t + 256 * u, row = f >> 4, c4 = (f & 15) << 2;
        *(float4*)&tile[row][c4] = *(const float4*)&src[(size_t)(r0 + row) * E_ + c0 + c4];
    }
    __syncthreads();
    #pragma unroll
    for (int u = 0; u < 4; ++u) {
        int f = t + 256 * u, c = f >> 4, r4 = (f & 15) << 2;
        ushort4 hv;
        hv.x = f2bf(tile[r4 + 0][c]);
        hv.y = f2bf(tile[r4 + 1][c]);
        hv.z = f2bf(tile[r4 + 2][c]);
        hv.w = f2bf(tile[r4 + 3][c]);
        *(ushort4*)&dst[(size_t)(c0 + c) * E_ + r0 + r4] = hv;
    }
}

// ---------------------------------------------------------------------------
// Prep C: transpose+split W1 (E x HID fp32) -> W1t hi/lo (HID x E, bf16).
// ---------------------------------------------------------------------------
__global__ __launch_bounds__(256) void w1prep(
    const float* __restrict__ W1,
    unsigned short* __restrict__ Th, unsigned short* __restrict__ Tl)
{
    __shared__ float tile[64][65];
    const int t  = threadIdx.x;
    const int r0 = blockIdx.y * 64, c0 = blockIdx.x * 64;

    #pragma unroll
    for (int u = 0; u < 4; ++u) {
        int f = t + 256 * u, row = f >> 4, c4 = (f & 15) << 2;
        *(float4*)&tile[row][c4] = *(const float4*)&W1[(size_t)(r0 + row) * HID_ + c0 + c4];
    }
    __syncthreads();
    #pragma unroll
    for (int u = 0; u < 4; ++u) {
        int f = t + 256 * u, c = f >> 4, r4 = (f & 15) << 2;
        ushort4 hv, lv;
        float v0 = tile[r4 + 0][c], v1 = tile[r4 + 1][c];
        float v2 = tile[r4 + 2][c], v3 = tile[r4 + 3][c];
        hv.x = f2bf(v0); lv.x = f2bf(v0 - bf2f(hv.x));
        hv.y = f2bf(v1); lv.y = f2bf(v1 - bf2f(hv.y));
        hv.z = f2bf(v2); lv.z = f2bf(v2 - bf2f(hv.z));
        hv.w = f2bf(v3); lv.w = f2bf(v3 - bf2f(hv.w));
        *(ushort4*)&Th[(size_t)(c0 + c) * E_ + r0 + r4] = hv;
        *(ushort4*)&Tl[(size_t)(c0 + c) * E_ + r0 + r4] = lv;
    }
}

// ---------------------------------------------------------------------------
// Kernel 1: QKV projection via MFMA. C = z @ W + b (2-term split on z),
// bf16 output scattered to (BH, L, DH). Block 128x128, 4 waves.
// ---------------------------------------------------------------------------
__global__ __launch_bounds__(256) void qkv_mfma(
    const unsigned short* __restrict__ zhi, const unsigned short* __restrict__ zlo,
    const unsigned short* __restrict__ Tq, const unsigned short* __restrict__ Tk,
    const unsigned short* __restrict__ Tv,
    const float* __restrict__ bq, const float* __restrict__ bk,
    const float* __restrict__ bv,
    unsigned short* __restrict__ Qo, unsigned short* __restrict__ Ko,
    unsigned short* __restrict__ Vo)
{
    const int which = blockIdx.z;
    const unsigned short* Wt = (which == 0) ? Tq : (which == 1) ? Tk : Tv;
    const float* bias = (which == 0) ? bq : (which == 1) ? bk : bv;
    unsigned short* out = (which == 0) ? Qo : (which == 1) ? Ko : Vo;

    __shared__ unsigned short Ah[128 * 64];
    __shared__ unsigned short Al[128 * 64];
    __shared__ unsigned short Bs[128 * 64];

    const int t    = threadIdx.x;
    const int lane = t & 63;
    const int w    = t >> 6;
    const int l31  = lane & 31;
    const int hq   = lane >> 5;
    const int m0   = blockIdx.x * 128;
    const int n0   = blockIdx.y * 128;

    f32x16 acc[4] = {};

    for (int kc = 0; kc < 16; ++kc) {
        short8v sa[4], sb[4], sc[4];
        #pragma unroll
        for (int u = 0; u < 4; ++u) {
            int v = t + 256 * u, row = v >> 3, slt = v & 7;
            sa[u] = *(const short8v*)&zhi[(size_t)(m0 + row) * E_ + kc * 64 + slt * 8];
            sb[u] = *(const short8v*)&zlo[(size_t)(m0 + row) * E_ + kc * 64 + slt * 8];
            sc[u] = *(const short8v*)&Wt [(size_t)(n0 + row) * E_ + kc * 64 + slt * 8];
        }
        __syncthreads();
        #pragma unroll
        for (int u = 0; u < 4; ++u) {
            int v = t + 256 * u, row = v >> 3, slt = v & 7;
            int d = row * 64 + ((slt ^ (row & 7)) * 8);
            *(short8v*)&Ah[d] = sa[u];
            *(short8v*)&Al[d] = sb[u];
            *(short8v*)&Bs[d] = sc[u];
        }
        __syncthreads();

        #pragma unroll
        for (int ks = 0; ks < 4; ++ks) {
            int ar = w * 32 + l31;
            short8v fa = *(const short8v*)&Ah[ar * 64 + ((ks * 2 + hq) ^ (ar & 7)) * 8];
            short8v fl = *(const short8v*)&Al[ar * 64 + ((ks * 2 + hq) ^ (ar & 7)) * 8];
            #pragma unroll
            for (int tt = 0; tt < 4; ++tt) {
                int br = tt * 32 + l31;
                short8v fb = *(const short8v*)&Bs[br * 64 + ((ks * 2 + hq) ^ (br & 7)) * 8];
                acc[tt] = MFMA32(fa, fb, acc[tt]);
                acc[tt] = MFMA32(fl, fb, acc[tt]);
            }
        }
    }

    // epilogue: bias + scatter bf16 to (BH,L,DH)
    #pragma unroll
    for (int tt = 0; tt < 4; ++tt) {
        int n  = n0 + tt * 32 + l31;
        int h  = n >> 6, dh = n & 63;
        float bb = bias[n];
        #pragma unroll
        for (int r = 0; r < 16; ++r) {
            int m = m0 + w * 32 + (r & 3) + 8 * (r >> 2) + 4 * hq;
            int b = m >> 11, i = m & (L_ - 1);
            out[((size_t)(b * H_ + h) * L_ + i) * DH_ + dh] = f2bf(acc[tt][r] + bb);
        }
    }
}

// ---------------------------------------------------------------------------
// Kernel 2: column stats via MFMA (unchanged from round 3).
// ---------------------------------------------------------------------------
__global__ __launch_bounds__(256) void col_stats_mfma(
    const unsigned short* __restrict__ Qb, const unsigned short* __restrict__ Kb,
    const float* __restrict__ x,
    float* __restrict__ Mo, float* __restrict__ Do)
{
    __shared__ unsigned short Qlds[32 * 64];
    __shared__ float xlds[L_];

    const int t    = threadIdx.x;
    const int lane = t & 63;
    const int wv   = t >> 6;
    const int l31  = lane & 31;
    const int hq   = lane >> 5;
    const int bh   = blockIdx.y;
    const int b    = bh >> 4;
    const int j0   = blockIdx.x * 128 + wv * 32;

    #pragma unroll
    for (int u = 0; u < 2; ++u) {
        int f = t + 256 * u;
        *(float4*)&xlds[f * 4] = *(const float4*)&x[(size_t)b * L_ + f * 4];
    }

    short8v kf[4];
    {
        const unsigned short* kp = Kb + ((size_t)bh * L_ + j0 + l31) * DH_ + hq * 8;
        #pragma unroll
        for (int c = 0; c < 4; ++c) kf[c] = *(const short8v*)(kp + c * 16);
    }

    float m[16], d[16];
    #pragma unroll
    for (int r = 0; r < 16; ++r) { m[r] = -1e30f; d[r] = 0.f; }

    for (int ich = 0; ich < L_ / 32; ++ich) {
        int row = t >> 3, sl = t & 7;
        short8v qv = *(const short8v*)&Qb[((size_t)bh * L_ + ich * 32 + row) * DH_ + sl * 8];
        __syncthreads();
        *(short8v*)&Qlds[row * 64 + (sl ^ (row & 7)) * 8] = qv;
        __syncthreads();

        f32x16 acc = {};
        #pragma unroll
        for (int c = 0; c < 4; ++c) {
            short8v qf = *(const short8v*)&Qlds[l31 * 64 + (((c * 2 + hq)) ^ (l31 & 7)) * 8];
            acc = MFMA32(kf[c], qf, acc);
        }

        float xi = xlds[ich * 32 + l31];
        #pragma unroll
        for (int r = 0; r < 16; ++r) {
            float s  = acc[r] * 0.125f;
            float mn = fmaxf(m[r], s);
            d[r] = d[r] * __expf(m[r] - mn) + xi * __expf(s - mn);
            m[r] = mn;
        }
    }

    #pragma unroll
    for (int r = 0; r < 16; ++r) {
        #pragma unroll
        for (int off = 16; off > 0; off >>= 1) {
            float m2 = __shfl_xor(m[r], off);
            float d2 = __shfl_xor(d[r], off);
            float M  = fmaxf(m[r], m2);
            d[r] = d[r] * __expf(m[r] - M) + d2 * __expf(m2 - M);
            m[r] = M;
        }
    }
    if (l31 == 0) {
        #pragma unroll
        for (int r = 0; r < 16; ++r) {
            int j = j0 + 4 * hq + (r & 3) + 8 * (r >> 2);
            Mo[(size_t)bh * L_ + j] = m[r];
            Do[(size_t)bh * L_ + j] = d[r];
        }
    }
}

// ---------------------------------------------------------------------------
// Kernel 3: Vt[bh][dh][j] = bf16( x_j * V[bh][j][dh] * exp(-M_j) / D_j )
// ---------------------------------------------------------------------------
__global__ __launch_bounds__(256) void vt_prep(
    const unsigned short* __restrict__ Vb, const float* __restrict__ x,
    const float* __restrict__ Mo, const float* __restrict__ Do,
    unsigned short* __restrict__ Vt)
{
    const int bh = blockIdx.y;
    const int b  = bh >> 4;
    const int j  = blockIdx.x * 256 + threadIdx.x;
    const float s = x[(size_t)b * L_ + j] * __expf(-Mo[(size_t)bh * L_ + j]) / Do[(size_t)bh * L_ + j];
    const unsigned short* vp = Vb + ((size_t)bh * L_ + j) * DH_;
    #pragma unroll
    for (int c = 0; c < 16; ++c) {
        ushort4 v = *(const ushort4*)&vp[c * 4];
        Vt[((size_t)bh * DH_ + c * 4 + 0) * L_ + j] = f2bf(bf2f(v.x) * s);
        Vt[((size_t)bh * DH_ + c * 4 + 1) * L_ + j] = f2bf(bf2f(v.y) * s);
        Vt[((size_t)bh * DH_ + c * 4 + 2) * L_ + j] = f2bf(bf2f(v.z) * s);
        Vt[((size_t)bh * DH_ + c * 4 + 3) * L_ + j] = f2bf(bf2f(v.w) * s);
    }
}

// ---------------------------------------------------------------------------
// Kernel 4: attention output via MFMA; epilogue writes O as bf16 hi/lo planes.
// ---------------------------------------------------------------------------
__global__ __launch_bounds__(256) void attn_out_mfma(
    const unsigned short* __restrict__ Qb, const unsigned short* __restrict__ Kb,
    const unsigned short* __restrict__ Vt, const float* __restrict__ x,
    unsigned short* __restrict__ Ohi, unsigned short* __restrict__ Olo)
{
    __shared__ unsigned short Klds[64 * 64];
    __shared__ unsigned short Vlds[64 * 64];
    __shared__ unsigned short Plds[4 * 32 * 64];

    const int t    = threadIdx.x;
    const int lane = t & 63;
    const int wv   = t >> 6;
    const int l31  = lane & 31;
    const int hq   = lane >> 5;
    const int bh   = blockIdx.y;
    const int b    = bh >> 4, hh = bh & 15;
    const int iw   = blockIdx.x * 128 + wv * 32;

    short8v qf[4];
    {
        const unsigned short* qp = Qb + ((size_t)bh * L_ + iw + l31) * DH_ + hq * 8;
        #pragma unroll
        for (int c = 0; c < 4; ++c) qf[c] = *(const short8v*)(qp + c * 16);
    }

    f32x16 accO0 = {}, accO1 = {};
    char* Pw = (char*)(Plds + wv * 2048);

    for (int jt = 0; jt < L_ / 64; ++jt) {
        int j0 = jt * 64;
        short8v kv[2], vv[2];
        #pragma unroll
        for (int u = 0; u < 2; ++u) {
            int f = t + 256 * u, row = f >> 3, sl = f & 7;
            kv[u] = *(const short8v*)&Kb[((size_t)bh * L_ + j0 + row) * DH_ + sl * 8];
            vv[u] = *(const short8v*)&Vt[((size_t)bh * DH_ + row) * L_ + j0 + sl * 8];
        }
        __syncthreads();
        #pragma unroll
        for (int u = 0; u < 2; ++u) {
            int f = t + 256 * u, row = f >> 3, sl = f & 7;
            *(short8v*)&Klds[row * 64 + (sl ^ (row & 7)) * 8] = kv[u];
            *(short8v*)&Vlds[row * 64 + (sl ^ (row & 7)) * 8] = vv[u];
        }
        __syncthreads();

        #pragma unroll
        for (int js = 0; js < 2; ++js) {
            f32x16 as = {};
            #pragma unroll
            for (int c = 0; c < 4; ++c) {
                int krow = js * 32 + l31;
                short8v kfr = *(const short8v*)&Klds[krow * 64 + ((c * 2 + hq) ^ (krow & 7)) * 8];
                as = MFMA32(kfr, qf[c], as);
            }
            #pragma unroll
            for (int q = 0; q < 4; ++q) {
                float p0 = __expf(as[4 * q + 0] * 0.125f);
                float p1 = __expf(as[4 * q + 1] * 0.125f);
                float p2 = __expf(as[4 * q + 2] * 0.125f);
                float p3 = __expf(as[4 * q + 3] * 0.125f);
                uint2 pk;
                pk.x = (unsigned)f2bf(p0) | ((unsigned)f2bf(p1) << 16);
                pk.y = (unsigned)f2bf(p2) | ((unsigned)f2bf(p3) << 16);
                int jb   = js * 64 + 8 * hq + 16 * q;
                *(uint2*)(Pw + l31 * 128 + (jb ^ ((l31 & 7) << 4))) = pk;
            }
        }

        short8v pf[4];
        #pragma unroll
        for (int c = 0; c < 4; ++c)
            pf[c] = *(const short8v*)(Pw + l31 * 128 + (((c * 16 + hq * 8) * 2) ^ ((l31 & 7) << 4)));
        #pragma unroll
        for (int c = 0; c < 4; ++c) {
            int r0 = l31, r1 = 32 + l31;
            short8v vf0 = *(const short8v*)&Vlds[r0 * 64 + ((c * 2 + hq) ^ (r0 & 7)) * 8];
            short8v vf1 = *(const short8v*)&Vlds[r1 * 64 + ((c * 2 + hq) ^ (r1 & 7)) * 8];
            accO0 = MFMA32(pf[c], vf0, accO0);
            accO1 = MFMA32(pf[c], vf1, accO1);
        }
        __syncthreads();
    }

    #pragma unroll
    for (int q = 0; q < 4; ++q) {
        float4 xq = *(const float4*)&x[(size_t)b * L_ + iw + 4 * hq + 8 * q];
        const float xs[4] = { xq.x, xq.y, xq.z, xq.w };
        #pragma unroll
        for (int k = 0; k < 4; ++k) {
            int r    = q * 4 + k;
            int irow = iw + 4 * hq + 8 * q + k;
            size_t base = ((size_t)b * L_ + irow) * E_ + hh * DH_;
            float v0 = accO0[r] * xs[k];
            float v1 = accO1[r] * xs[k];
            unsigned short h0 = f2bf(v0), h1 = f2bf(v1);
            Ohi[base + l31]      = h0;
            Olo[base + l31]      = f2bf(v0 - bf2f(h0));
            Ohi[base + 32 + l31] = h1;
            Olo[base + 32 + l31] = f2bf(v1 - bf2f(h1));
        }
    }
}

// ---------------------------------------------------------------------------
// Kernel 5a: y_init — y[i] = b2[0].
// ---------------------------------------------------------------------------
__global__ __launch_bounds__(256) void y_init(float* __restrict__ y, const float* __restrict__ b2)
{
    y[blockIdx.x * 256 + threadIdx.x] = b2[0];
}

// ---------------------------------------------------------------------------
// Kernel 5b: fused MLP via MFMA (3-term split). Block = 256 rows x 128 hid,
// 8 waves; K-chunk 64; gelu+W2 dot in epilogue; atomicAdd partial y.
// ---------------------------------------------------------------------------
__global__ __launch_bounds__(512) void mlp_mfma(
    const unsigned short* __restrict__ Oh_g, const unsigned short* __restrict__ Ol_g,
    const unsigned short* __restrict__ W1h, const unsigned short* __restrict__ W1l,
    const float* __restrict__ b1, const float* __restrict__ W2,
    float* __restrict__ y)
{
    __shared__ unsigned short Oh[256 * 64];
    __shared__ unsigned short Ol[256 * 64];
    __shared__ unsigned short Wh[128 * 64];
    __shared__ unsigned short Wl[128 * 64];

    const int t    = threadIdx.x;
    const int lane = t & 63;
    const int w    = t >> 6;
    const int l31  = lane & 31;
    const int hq   = lane >> 5;
    const int m0   = blockIdx.x * 256;
    const int n0   = blockIdx.y * 128;

    f32x16 acc[4] = {};

    for (int kc = 0; kc < 16; ++kc) {
        short8v so[4], sp[4], swh[2], swl[2];
        #pragma unroll
        for (int u = 0; u < 4; ++u) {
            int v = t + 512 * u, row = v >> 3, slt = v & 7;
            so[u] = *(const short8v*)&Oh_g[(size_t)(m0 + row) * E_ + kc * 64 + slt * 8];
            sp[u] = *(const short8v*)&Ol_g[(size_t)(m0 + row) * E_ + kc * 64 + slt * 8];
        }
        #pragma unroll
        for (int u = 0; u < 2; ++u) {
            int v = t + 512 * u, row = v >> 3, slt = v & 7;
            swh[u] = *(const short8v*)&W1h[(size_t)(n0 + row) * E_ + kc * 64 + slt * 8];
            swl[u] = *(const short8v*)&W1l[(size_t)(n0 + row) * E_ + kc * 64 + slt * 8];
        }
        __syncthreads();
        #pragma unroll
        for (int u = 0; u < 4; ++u) {
            int v = t + 512 * u, row = v >> 3, slt = v & 7;
            int d = row * 64 + ((slt ^ (row & 7)) * 8);
            *(short8v*)&Oh[d] = so[u];
            *(short8v*)&Ol[d] = sp[u];
        }
        #pragma unroll
        for (int u = 0; u < 2; ++u) {
            int v = t + 512 * u, row = v >> 3, slt = v & 7;
            int d = row * 64 + ((slt ^ (row & 7)) * 8);
            *(short8v*)&Wh[d] = swh[u];
            *(short8v*)&Wl[d] = swl[u];
        }
        __syncthreads();

        #pragma unroll
        for (int ks = 0; ks < 4; ++ks) {
            int ar = w * 32 + l31;
            short8v fa = *(const short8v*)&Oh[ar * 64 + ((ks * 2 + hq) ^ (ar & 7)) * 8];
            short8v fp = *(const short8v*)&Ol[ar * 64 + ((ks * 2 + hq) ^ (ar & 7)) * 8];
            #pragma unroll
            for (int tt = 0; tt < 4; ++tt) {
                int br = tt * 32 + l31;
                short8v fbh = *(const short8v*)&Wh[br * 64 + ((ks * 2 + hq) ^ (br & 7)) * 8];
                short8v fbl = *(const short8v*)&Wl[br * 64 + ((ks * 2 + hq) ^ (br & 7)) * 8];
                acc[tt] = MFMA32(fa, fbh, acc[tt]);
                acc[tt] = MFMA32(fa, fbl, acc[tt]);
                acc[tt] = MFMA32(fp, fbh, acc[tt]);
            }
        }
    }

    // epilogue: gelu + W2 dot, reduce over 32 lanes, atomicAdd per row.
    float yloc[16] = {};
    #pragma unroll
    for (int tt = 0; tt < 4; ++tt) {
        int hid = n0 + tt * 32 + l31;
        float bb = b1[hid], w2 = W2[hid];
        #pragma unroll
        for (int r = 0; r < 16; ++r) {
            float hv = acc[tt][r] + bb;
            float g  = 0.5f * hv * (1.0f + erff(hv * 0.70710678118654752f));
            yloc[r] = fmaf(g, w2, yloc[r]);
        }
    }
    #pragma unroll
    for (int r = 0; r < 16; ++r) {
        #pragma unroll
        for (int off = 16; off > 0; off >>= 1)
            yloc[r] += __shfl_xor(yloc[r], off);
    }
    if (l31 == 0) {
        #pragma unroll
        for (int r = 0; r < 16; ++r) {
            int m = m0 + w * 32 + (r & 3) + 8 * (r >> 2) + 4 * hq;
            atomicAdd(&y[m], yloc[r]);
        }
    }
}

// ---------------------------------------------------------------------------
extern "C" void kernel_launch(void* const* d_in, const int* in_sizes, int n_in,
                              void* d_out, int out_size, void* d_ws, size_t ws_size,
                              hipStream_t stream)
{
    const float* x  = (const float*)d_in[0];
    const float* z  = (const float*)d_in[1];
    const float* Wq = (const float*)d_in[2];
    const float* bq = (const float*)d_in[3];
    const float* Wk = (const float*)d_in[4];
    const float* bk = (const float*)d_in[5];
    const float* Wv = (const float*)d_in[6];
    const float* bv = (const float*)d_in[7];
    const float* W1 = (const float*)d_in[8];
    const float* b1 = (const float*)d_in[9];
    const float* W2 = (const float*)d_in[10];
    const float* b2 = (const float*)d_in[11];
    float* y = (float*)d_out;

    const size_t NQ = (size_t)BH_ * L_ * DH_;        // 4.19M
    unsigned short* p = (unsigned short*)d_ws;
    unsigned short* Qb  = p;  p += NQ;
    unsigned short* Kb  = p;  p += NQ;
    unsigned short* Vb  = p;  p += NQ;
    unsigned short* Vt  = p;  p += NQ;
    unsigned short* zhi = p;  p += (size_t)NROW_ * E_;
    unsigned short* zlo = p;  p += (size_t)NROW_ * E_;
    unsigned short* Tq  = p;  p += (size_t)E_ * E_;
    unsigned short* Tk  = p;  p += (size_t)E_ * E_;
    unsigned short* Tv  = p;  p += (size_t)E_ * E_;
    unsigned short* W1h = p;  p += (size_t)HID_ * E_;
    unsigned short* W1l = p;  p += (size_t)HID_ * E_;
    unsigned short* Ohi = p;  p += (size_t)NROW_ * E_;
    unsigned short* Olo = p;  p += (size_t)NROW_ * E_;
    float* Mw = (float*)p;
    float* Dw = Mw + (size_t)BH_ * L_;

    split_z<<<dim3((NROW_ * E_) / (256 * 8)), 256, 0, stream>>>(z, zhi, zlo);
    wprep3 <<<dim3(E_ / 64, E_ / 64, 3), 256, 0, stream>>>(Wq, Wk, Wv, Tq, Tk, Tv);
    w1prep <<<dim3(HID_ / 64, E_ / 64), 256, 0, stream>>>(W1, W1h, W1l);

    qkv_mfma<<<dim3(NROW_ / 128, E_ / 128, 3), 256, 0, stream>>>(
        zhi, zlo, Tq, Tk, Tv, bq, bk, bv, Qb, Kb, Vb);

    col_stats_mfma<<<dim3(L_ / 128, BH_), 256, 0, stream>>>(Qb, Kb, x, Mw, Dw);

    vt_prep<<<dim3(L_ / 256, BH_), 256, 0, stream>>>(Vb, x, Mw, Dw, Vt);

    attn_out_mfma<<<dim3(L_ / 128, BH_), 256, 0, stream>>>(Qb, Kb, Vt, x, Ohi, Olo);

    y_init<<<dim3(NROW_ / 256), 256, 0, stream>>>(y, b2);

    mlp_mfma<<<dim3(NROW_ / 256, HID_ / 128), 512, 0, stream>>>(
        Ohi, Olo, W1h, W1l, b1, W2, y);
}

// Round 5
// 231.802 us; speedup vs baseline: 10.6925x; 1.5002x over previous
//
#include <hip/hip_runtime.h>
#include <hip/hip_bf16.h>
#include <math.h>

#define B_    2
#define L_    2048
#define E_    1024
#define H_    16
#define DH_   64
#define HID_  4096
#define NROW_ (B_*L_)   // 4096
#define BH_   (B_*H_)   // 32

typedef __attribute__((ext_vector_type(8)))  short    short8v;
typedef _Float16 half8v __attribute__((ext_vector_type(8)));
typedef __attribute__((ext_vector_type(16))) float    f32x16;

#define MFMA32(A, Bv, C) __builtin_amdgcn_mfma_f32_32x32x16_bf16((A), (Bv), (C), 0, 0, 0)
#define MFMAH(A, Bv, C)  __builtin_amdgcn_mfma_f32_32x32x16_f16((A), (Bv), (C), 0, 0, 0)

__device__ __forceinline__ unsigned short f2bf(float f) {
    union { float f; unsigned u; } v; v.f = f;
    unsigned r = v.u + 0x7FFF + ((v.u >> 16) & 1);   // RNE
    return (unsigned short)(r >> 16);
}
__device__ __forceinline__ float bf2f(unsigned short u) {
    union { unsigned u; float f; } v; v.u = ((unsigned)u) << 16;
    return v.f;
}

// async global->LDS, 16B per lane. Dest is wave-uniform base + lane*16.
__device__ __forceinline__ void gl_lds16(const void* g, void* l) {
    __builtin_amdgcn_global_load_lds(
        (const __attribute__((address_space(1))) unsigned int*)g,
        (__attribute__((address_space(3))) unsigned int*)l, 16, 0, 0);
}

// Abramowitz-Stegun 7.1.26, |abs err| < 1.5e-7
__device__ __forceinline__ float erf_fast(float v) {
    float a = fabsf(v);
    float t = __builtin_amdgcn_rcpf(1.0f + 0.3275911f * a);
    float p = t * (0.254829592f + t * (-0.284496736f + t * (1.421413741f +
              t * (-1.453152027f + t * 1.061405429f))));
    float r = 1.0f - p * __expf(-a * a);
    return copysignf(r, v);
}

// ---------------------------------------------------------------------------
// Prep A: cast z (fp32) -> zh (fp16), same layout.
// ---------------------------------------------------------------------------
__global__ __launch_bounds__(256) void zh_prep(
    const float* __restrict__ z, _Float16* __restrict__ zh)
{
    const size_t i = ((size_t)blockIdx.x * 256 + threadIdx.x) * 8;
    float4 a = *(const float4*)&z[i];
    float4 b = *(const float4*)&z[i + 4];
    union { _Float16 h[8]; half8v v; } o;
    o.h[0] = (_Float16)a.x; o.h[1] = (_Float16)a.y;
    o.h[2] = (_Float16)a.z; o.h[3] = (_Float16)a.w;
    o.h[4] = (_Float16)b.x; o.h[5] = (_Float16)b.y;
    o.h[6] = (_Float16)b.z; o.h[7] = (_Float16)b.w;
    *(half8v*)&zh[i] = o.v;
}

// ---------------------------------------------------------------------------
// Prep B: transpose+cast Wq/Wk/Wv (ExE fp32) -> T* (n-major fp16).
// ---------------------------------------------------------------------------
__global__ __launch_bounds__(256) void wprep3(
    const float* __restrict__ Wq, const float* __restrict__ Wk,
    const float* __restrict__ Wv,
    _Float16* __restrict__ Tq, _Float16* __restrict__ Tk,
    _Float16* __restrict__ Tv)
{
    const float* src = (blockIdx.z == 0) ? Wq : (blockIdx.z == 1) ? Wk : Wv;
    _Float16*    dst = (blockIdx.z == 0) ? Tq : (blockIdx.z == 1) ? Tk : Tv;
    __shared__ float tile[64][65];
    const int t  = threadIdx.x;
    const int r0 = blockIdx.y * 64, c0 = blockIdx.x * 64;
    #pragma unroll
    for (int u = 0; u < 4; ++u) {
        int f = t + 256 * u, row = f >> 4, c4 = (f & 15) << 2;
        *(float4*)&tile[row][c4] = *(const float4*)&src[(size_t)(r0 + row) * E_ + c0 + c4];
    }
    __syncthreads();
    #pragma unroll
    for (int u = 0; u < 4; ++u) {
        int f = t + 256 * u, c = f >> 4, r4 = (f & 15) << 2;
        union { _Float16 h[4]; uint2 u2; } pk;
        pk.h[0] = (_Float16)tile[r4 + 0][c];
        pk.h[1] = (_Float16)tile[r4 + 1][c];
        pk.h[2] = (_Float16)tile[r4 + 2][c];
        pk.h[3] = (_Float16)tile[r4 + 3][c];
        *(uint2*)&dst[(size_t)(c0 + c) * E_ + r0 + r4] = pk.u2;
    }
}

// ---------------------------------------------------------------------------
// Prep C: transpose+cast W1 (E x HID fp32) -> W1t (HID x E fp16).
// ---------------------------------------------------------------------------
__global__ __launch_bounds__(256) void w1prep(
    const float* __restrict__ W1, _Float16* __restrict__ W1t)
{
    __shared__ float tile[64][65];
    const int t  = threadIdx.x;
    const int r0 = blockIdx.y * 64, c0 = blockIdx.x * 64;
    #pragma unroll
    for (int u = 0; u < 4; ++u) {
        int f = t + 256 * u, row = f >> 4, c4 = (f & 15) << 2;
        *(float4*)&tile[row][c4] = *(const float4*)&W1[(size_t)(r0 + row) * HID_ + c0 + c4];
    }
    __syncthreads();
    #pragma unroll
    for (int u = 0; u < 4; ++u) {
        int f = t + 256 * u, c = f >> 4, r4 = (f & 15) << 2;
        union { _Float16 h[4]; uint2 u2; } pk;
        pk.h[0] = (_Float16)tile[r4 + 0][c];
        pk.h[1] = (_Float16)tile[r4 + 1][c];
        pk.h[2] = (_Float16)tile[r4 + 2][c];
        pk.h[3] = (_Float16)tile[r4 + 3][c];
        *(uint2*)&W1t[(size_t)(c0 + c) * E_ + r0 + r4] = pk.u2;
    }
}

// ---------------------------------------------------------------------------
// Kernel 1: QKV projection, fp16 1-term MFMA. Block 256x256, 8 waves (2m x 4n),
// wave tile 128x64 (acc[4][2]). global_load_lds staging, swizzled source.
// bf16 output scattered to (BH, L, DH).
// ---------------------------------------------------------------------------
__global__ __launch_bounds__(512) void qkv_mfma(
    const _Float16* __restrict__ zh,
    const _Float16* __restrict__ Tq, const _Float16* __restrict__ Tk,
    const _Float16* __restrict__ Tv,
    const float* __restrict__ bq, const float* __restrict__ bk,
    const float* __restrict__ bv,
    unsigned short* __restrict__ Qo, unsigned short* __restrict__ Ko,
    unsigned short* __restrict__ Vo)
{
    const int which = blockIdx.z;
    const _Float16* Wt = (which == 0) ? Tq : (which == 1) ? Tk : Tv;
    const float*  bias = (which == 0) ? bq : (which == 1) ? bk : bv;
    unsigned short* out = (which == 0) ? Qo : (which == 1) ? Ko : Vo;

    __shared__ _Float16 Ah[256 * 64];
    __shared__ _Float16 Bs[256 * 64];

    const int t    = threadIdx.x;
    const int lane = t & 63;
    const int w    = t >> 6;
    const int l31  = lane & 31;
    const int hq   = lane >> 5;
    const int wm   = w >> 2, wn = w & 3;
    const int m0   = blockIdx.x * 256;
    const int n0   = blockIdx.y * 256;

    f32x16 acc[4][2] = {};

    for (int kc = 0; kc < 16; ++kc) {
        __syncthreads();
        #pragma unroll
        for (int u = 0; u < 4; ++u) {
            int ch  = w * 4 + u;
            int row = ch * 8 + (lane >> 3), s = lane & 7;
            gl_lds16(&zh[(size_t)(m0 + row) * E_ + kc * 64 + ((s ^ (row & 7)) << 3)], &Ah[ch * 512]);
            gl_lds16(&Wt[(size_t)(n0 + row) * E_ + kc * 64 + ((s ^ (row & 7)) << 3)], &Bs[ch * 512]);
        }
        __syncthreads();

        #pragma unroll
        for (int ks = 0; ks < 4; ++ks) {
            half8v fb[2];
            #pragma unroll
            for (int nb = 0; nb < 2; ++nb) {
                int br = wn * 64 + nb * 32 + l31;
                fb[nb] = *(const half8v*)&Bs[br * 64 + (((ks * 2 + hq) ^ (br & 7)) << 3)];
            }
            #pragma unroll
            for (int mb = 0; mb < 4; ++mb) {
                int ar = wm * 128 + mb * 32 + l31;
                half8v fa = *(const half8v*)&Ah[ar * 64 + (((ks * 2 + hq) ^ (ar & 7)) << 3)];
                acc[mb][0] = MFMAH(fa, fb[0], acc[mb][0]);
                acc[mb][1] = MFMAH(fa, fb[1], acc[mb][1]);
            }
        }
    }

    // epilogue: bias + bf16 scatter to (BH,L,DH)
    #pragma unroll
    for (int nb = 0; nb < 2; ++nb) {
        int n  = n0 + wn * 64 + nb * 32 + l31;
        int h  = n >> 6, dh = n & 63;
        float bb = bias[n];
        #pragma unroll
        for (int mb = 0; mb < 4; ++mb) {
            #pragma unroll
            for (int r = 0; r < 16; ++r) {
                int m  = m0 + wm * 128 + mb * 32 + (r & 3) + 8 * (r >> 2) + 4 * hq;
                int b  = m >> 11, i = m & (L_ - 1);
                out[((size_t)(b * H_ + h) * L_ + i) * DH_ + dh] = f2bf(acc[mb][nb][r] + bb);
            }
        }
    }
}

// ---------------------------------------------------------------------------
// Kernel 2: column sums D_j = sum_i x_i*exp(S_ij) (m=0; S range is tiny).
// S^T = K.Q^T via bf16 MFMA; wave owns 32 j (K-frags in regs); i staged 128/iter.
// ---------------------------------------------------------------------------
__global__ __launch_bounds__(256) void col_stats_mfma(
    const unsigned short* __restrict__ Qb, const unsigned short* __restrict__ Kb,
    const float* __restrict__ x, float* __restrict__ Do)
{
    __shared__ unsigned short Qlds[128 * 64];
    __shared__ float xlds[L_];

    const int t    = threadIdx.x;
    const int lane = t & 63;
    const int wv   = t >> 6;
    const int l31  = lane & 31;
    const int hq   = lane >> 5;
    const int bh   = blockIdx.y;
    const int b    = bh >> 4;
    const int j0   = blockIdx.x * 128 + wv * 32;

    #pragma unroll
    for (int u = 0; u < 2; ++u) {
        int f = t + 256 * u;
        *(float4*)&xlds[f * 4] = *(const float4*)&x[(size_t)b * L_ + f * 4];
    }

    short8v kf[4];
    {
        const unsigned short* kp = Kb + ((size_t)bh * L_ + j0 + l31) * DH_ + hq * 8;
        #pragma unroll
        for (int c = 0; c < 4; ++c) kf[c] = *(const short8v*)(kp + c * 16);
    }

    float d[16];
    #pragma unroll
    for (int r = 0; r < 16; ++r) d[r] = 0.f;

    for (int ich = 0; ich < L_ / 128; ++ich) {
        __syncthreads();
        #pragma unroll
        for (int u = 0; u < 4; ++u) {
            int ch  = wv * 4 + u;
            int row = ch * 8 + (lane >> 3), s = lane & 7;
            gl_lds16(&Qb[((size_t)bh * L_ + ich * 128 + row) * DH_ + ((s ^ (row & 7)) << 3)],
                     &Qlds[ch * 512]);
        }
        __syncthreads();

        #pragma unroll
        for (int cc = 0; cc < 4; ++cc) {
            f32x16 acc = {};
            #pragma unroll
            for (int c = 0; c < 4; ++c) {
                int qr = cc * 32 + l31;
                short8v qv = *(const short8v*)&Qlds[qr * 64 + (((c * 2 + hq) ^ (qr & 7)) << 3)];
                acc = MFMA32(kf[c], qv, acc);
            }
            float xi = xlds[ich * 128 + cc * 32 + l31];
            #pragma unroll
            for (int r = 0; r < 16; ++r)
                d[r] += xi * __expf(acc[r] * 0.125f);
        }
    }

    #pragma unroll
    for (int r = 0; r < 16; ++r) {
        #pragma unroll
        for (int off = 16; off > 0; off >>= 1)
            d[r] += __shfl_xor(d[r], off);
    }
    if (l31 == 0) {
        #pragma unroll
        for (int r = 0; r < 16; ++r)
            Do[(size_t)bh * L_ + j0 + 4 * hq + (r & 3) + 8 * (r >> 2)] = d[r];
    }
}

// ---------------------------------------------------------------------------
// Kernel 3: Vt[bh][dh][j] = bf16( x_j * V[bh][j][dh] / D_j )
// ---------------------------------------------------------------------------
__global__ __launch_bounds__(256) void vt_prep(
    const unsigned short* __restrict__ Vb, const float* __restrict__ x,
    const float* __restrict__ Do, unsigned short* __restrict__ Vt)
{
    const int bh = blockIdx.y;
    const int b  = bh >> 4;
    const int j  = blockIdx.x * 256 + threadIdx.x;
    const float s = x[(size_t)b * L_ + j] / Do[(size_t)bh * L_ + j];
    const unsigned short* vp = Vb + ((size_t)bh * L_ + j) * DH_;
    #pragma unroll
    for (int c = 0; c < 16; ++c) {
        ushort4 v = *(const ushort4*)&vp[c * 4];
        Vt[((size_t)bh * DH_ + c * 4 + 0) * L_ + j] = f2bf(bf2f(v.x) * s);
        Vt[((size_t)bh * DH_ + c * 4 + 1) * L_ + j] = f2bf(bf2f(v.y) * s);
        Vt[((size_t)bh * DH_ + c * 4 + 2) * L_ + j] = f2bf(bf2f(v.z) * s);
        Vt[((size_t)bh * DH_ + c * 4 + 3) * L_ + j] = f2bf(bf2f(v.w) * s);
    }
}

// ---------------------------------------------------------------------------
// Kernel 4: attention output. P = exp(S) (m=0), O = x_i * (P @ Vt^T).
// gload staging; epilogue writes Of fp16 (B*L, E) row-major.
// ---------------------------------------------------------------------------
__global__ __launch_bounds__(256) void attn_out_mfma(
    const unsigned short* __restrict__ Qb, const unsigned short* __restrict__ Kb,
    const unsigned short* __restrict__ Vt, const float* __restrict__ x,
    _Float16* __restrict__ Of)
{
    __shared__ unsigned short Klds[64 * 64];
    __shared__ unsigned short Vlds[64 * 64];
    __shared__ unsigned short Plds[4 * 32 * 64];

    const int t    = threadIdx.x;
    const int lane = t & 63;
    const int wv   = t >> 6;
    const int l31  = lane & 31;
    const int hq   = lane >> 5;
    const int bh   = blockIdx.y;
    const int b    = bh >> 4, hh = bh & 15;
    const int iw   = blockIdx.x * 128 + wv * 32;

    short8v qf[4];
    {
        const unsigned short* qp = Qb + ((size_t)bh * L_ + iw + l31) * DH_ + hq * 8;
        #pragma unroll
        for (int c = 0; c < 4; ++c) qf[c] = *(const short8v*)(qp + c * 16);
    }

    f32x16 accO0 = {}, accO1 = {};
    char* Pw = (char*)(Plds + wv * 2048);

    for (int jt = 0; jt < L_ / 64; ++jt) {
        int j0 = jt * 64;
        __syncthreads();
        #pragma unroll
        for (int u = 0; u < 2; ++u) {
            int ch  = wv * 2 + u;
            int row = ch * 8 + (lane >> 3), s = lane & 7;
            gl_lds16(&Kb[((size_t)bh * L_ + j0 + row) * DH_ + ((s ^ (row & 7)) << 3)], &Klds[ch * 512]);
            gl_lds16(&Vt[((size_t)bh * DH_ + row) * L_ + j0 + ((s ^ (row & 7)) << 3)], &Vlds[ch * 512]);
        }
        __syncthreads();

        #pragma unroll
        for (int js = 0; js < 2; ++js) {
            f32x16 as = {};
            #pragma unroll
            for (int c = 0; c < 4; ++c) {
                int krow = js * 32 + l31;
                short8v kfr = *(const short8v*)&Klds[krow * 64 + (((c * 2 + hq) ^ (krow & 7)) << 3)];
                as = MFMA32(kfr, qf[c], as);
            }
            #pragma unroll
            for (int q = 0; q < 4; ++q) {
                float p0 = __expf(as[4 * q + 0] * 0.125f);
                float p1 = __expf(as[4 * q + 1] * 0.125f);
                float p2 = __expf(as[4 * q + 2] * 0.125f);
                float p3 = __expf(as[4 * q + 3] * 0.125f);
                uint2 pk;
                pk.x = (unsigned)f2bf(p0) | ((unsigned)f2bf(p1) << 16);
                pk.y = (unsigned)f2bf(p2) | ((unsigned)f2bf(p3) << 16);
                int jb = js * 64 + 8 * hq + 16 * q;
                *(uint2*)(Pw + l31 * 128 + (jb ^ ((l31 & 7) << 4))) = pk;
            }
        }

        short8v pf[4];
        #pragma unroll
        for (int c = 0; c < 4; ++c)
            pf[c] = *(const short8v*)(Pw + l31 * 128 + (((c * 16 + hq * 8) * 2) ^ ((l31 & 7) << 4)));
        #pragma unroll
        for (int c = 0; c < 4; ++c) {
            int r0 = l31, r1 = 32 + l31;
            short8v vf0 = *(const short8v*)&Vlds[r0 * 64 + (((c * 2 + hq) ^ (r0 & 7)) << 3)];
            short8v vf1 = *(const short8v*)&Vlds[r1 * 64 + (((c * 2 + hq) ^ (r1 & 7)) << 3)];
            accO0 = MFMA32(pf[c], vf0, accO0);
            accO1 = MFMA32(pf[c], vf1, accO1);
        }
    }

    #pragma unroll
    for (int q = 0; q < 4; ++q) {
        float4 xq = *(const float4*)&x[(size_t)b * L_ + iw + 4 * hq + 8 * q];
        const float xs[4] = { xq.x, xq.y, xq.z, xq.w };
        #pragma unroll
        for (int k = 0; k < 4; ++k) {
            int r    = q * 4 + k;
            int irow = iw + 4 * hq + 8 * q + k;
            size_t base = ((size_t)b * L_ + irow) * E_ + hh * DH_;
            Of[base + l31]      = (_Float16)(accO0[r] * xs[k]);
            Of[base + 32 + l31] = (_Float16)(accO1[r] * xs[k]);
        }
    }
}

// ---------------------------------------------------------------------------
// Kernel 5a: y_init — y[i] = b2[0].
// ---------------------------------------------------------------------------
__global__ __launch_bounds__(256) void y_init(float* __restrict__ y, const float* __restrict__ b2)
{
    y[blockIdx.x * 256 + threadIdx.x] = b2[0];
}

// ---------------------------------------------------------------------------
// Kernel 5b: fused MLP, fp16 1-term MFMA. Block 256 rows x 256 hid, 8 waves
// (2m x 4n), wave tile 128x64 (acc[4][2]). gelu + W2-dot epilogue, atomicAdd.
// ---------------------------------------------------------------------------
__global__ __launch_bounds__(512) void mlp_mfma(
    const _Float16* __restrict__ Of, const _Float16* __restrict__ W1t,
    const float* __restrict__ b1, const float* __restrict__ W2,
    float* __restrict__ y)
{
    __shared__ _Float16 Oh[256 * 64];
    __shared__ _Float16 Wh[256 * 64];

    const int t    = threadIdx.x;
    const int lane = t & 63;
    const int w    = t >> 6;
    const int l31  = lane & 31;
    const int hq   = lane >> 5;
    const int wm   = w >> 2, wn = w & 3;
    const int m0   = blockIdx.x * 256;
    const int n0   = blockIdx.y * 256;

    f32x16 acc[4][2] = {};

    for (int kc = 0; kc < 16; ++kc) {
        __syncthreads();
        #pragma unroll
        for (int u = 0; u < 4; ++u) {
            int ch  = w * 4 + u;
            int row = ch * 8 + (lane >> 3), s = lane & 7;
            gl_lds16(&Of[(size_t)(m0 + row) * E_ + kc * 64 + ((s ^ (row & 7)) << 3)], &Oh[ch * 512]);
            gl_lds16(&W1t[(size_t)(n0 + row) * E_ + kc * 64 + ((s ^ (row & 7)) << 3)], &Wh[ch * 512]);
        }
        __syncthreads();

        #pragma unroll
        for (int ks = 0; ks < 4; ++ks) {
            half8v fb[2];
            #pragma unroll
            for (int nb = 0; nb < 2; ++nb) {
                int br = wn * 64 + nb * 32 + l31;
                fb[nb] = *(const half8v*)&Wh[br * 64 + (((ks * 2 + hq) ^ (br & 7)) << 3)];
            }
            #pragma unroll
            for (int mb = 0; mb < 4; ++mb) {
                int ar = wm * 128 + mb * 32 + l31;
                half8v fa = *(const half8v*)&Oh[ar * 64 + (((ks * 2 + hq) ^ (ar & 7)) << 3)];
                acc[mb][0] = MFMAH(fa, fb[0], acc[mb][0]);
                acc[mb][1] = MFMAH(fa, fb[1], acc[mb][1]);
            }
        }
    }

    // epilogue: gelu + W2 dot; reduce over 32 lanes; atomicAdd per row.
    const int hid0 = n0 + wn * 64 + l31;
    const float bb0 = b1[hid0],      w20 = W2[hid0];
    const float bb1 = b1[hid0 + 32], w21 = W2[hid0 + 32];
    #pragma unroll
    for (int mb = 0; mb < 4; ++mb) {
        #pragma unroll
        for (int r = 0; r < 16; ++r) {
            float h0 = acc[mb][0][r] + bb0;
            float h1 = acc[mb][1][r] + bb1;
            float s  = 0.5f * h0 * (1.0f + erf_fast(h0 * 0.70710678f)) * w20
                     + 0.5f * h1 * (1.0f + erf_fast(h1 * 0.70710678f)) * w21;
            #pragma unroll
            for (int off = 16; off > 0; off >>= 1) s += __shfl_xor(s, off);
            if (l31 == 0) {
                int m = m0 + wm * 128 + mb * 32 + (r & 3) + 8 * (r >> 2) + 4 * hq;
                atomicAdd(&y[m], s);
            }
        }
    }
}

// ---------------------------------------------------------------------------
extern "C" void kernel_launch(void* const* d_in, const int* in_sizes, int n_in,
                              void* d_out, int out_size, void* d_ws, size_t ws_size,
                              hipStream_t stream)
{
    const float* x  = (const float*)d_in[0];
    const float* z  = (const float*)d_in[1];
    const float* Wq = (const float*)d_in[2];
    const float* bq = (const float*)d_in[3];
    const float* Wk = (const float*)d_in[4];
    const float* bk = (const float*)d_in[5];
    const float* Wv = (const float*)d_in[6];
    const float* bv = (const float*)d_in[7];
    const float* W1 = (const float*)d_in[8];
    const float* b1 = (const float*)d_in[9];
    const float* W2 = (const float*)d_in[10];
    const float* b2 = (const float*)d_in[11];
    float* y = (float*)d_out;

    const size_t NQ = (size_t)BH_ * L_ * DH_;        // 4.19M elems
    unsigned short* p = (unsigned short*)d_ws;
    unsigned short* Qb  = p;  p += NQ;
    unsigned short* Kb  = p;  p += NQ;
    unsigned short* Vb  = p;  p += NQ;
    unsigned short* Vt  = p;  p += NQ;
    _Float16* zh  = (_Float16*)p;  p += (size_t)NROW_ * E_;
    _Float16* Tq  = (_Float16*)p;  p += (size_t)E_ * E_;
    _Float16* Tk  = (_Float16*)p;  p += (size_t)E_ * E_;
    _Float16* Tv  = (_Float16*)p;  p += (size_t)E_ * E_;
    _Float16* W1t = (_Float16*)p;  p += (size_t)HID_ * E_;
    _Float16* Ofp = (_Float16*)p;  p += (size_t)NROW_ * E_;
    float* Dw = (float*)p;

    zh_prep<<<dim3((NROW_ * E_) / (256 * 8)), 256, 0, stream>>>(z, zh);
    wprep3 <<<dim3(E_ / 64, E_ / 64, 3), 256, 0, stream>>>(Wq, Wk, Wv, Tq, Tk, Tv);
    w1prep <<<dim3(HID_ / 64, E_ / 64), 256, 0, stream>>>(W1, W1t);

    qkv_mfma<<<dim3(NROW_ / 256, E_ / 256, 3), 512, 0, stream>>>(
        zh, Tq, Tk, Tv, bq, bk, bv, Qb, Kb, Vb);

    col_stats_mfma<<<dim3(L_ / 128, BH_), 256, 0, stream>>>(Qb, Kb, x, Dw);

    vt_prep<<<dim3(L_ / 256, BH_), 256, 0, stream>>>(Vb, x, Dw, Vt);

    attn_out_mfma<<<dim3(L_ / 128, BH_), 256, 0, stream>>>(Qb, Kb, Vt, x, Ofp);

    y_init<<<dim3(NROW_ / 256), 256, 0, stream>>>(y, b2);

    mlp_mfma<<<dim3(NROW_ / 256, HID_ / 256), 512, 0, stream>>>(
        Ofp, W1t, b1, W2, y);
}